// Round 4
// baseline (715.440 us; speedup 1.0000x reference)
//
#include <hip/hip_runtime.h>
#include <hip/hip_bf16.h>
#include <cstdio>

// BlockAxialUp on MI355X, round 4: fuse QKV gemm + axial attention + out-proj
// into one per-sequence kernel (kills ~400 MB/dir of QKV/O HBM round-trips).
//
// ws layout (bytes):
//   0        wqkvT_h bf16 [768][256]   (rows: q 0:256, k 256:512, v 512:768)
//   393216   wqkvT_w
//   786432   woT_h  bf16 [256][256]
//   917504   woT_w
//   1048576  convT  bf16 [128][640]
//   1245184  xu     bf16 [65536][256]
//   34799616 ytmp   f32  [65536][128]
//   68354048 partial f32 [128][128][2]
//   68485120 stats  f32  [128][2]
// accb (ah+aw, bf16 [65536][256]) lives in d_out; final f32 output overwrites it.

typedef short bf16x8 __attribute__((ext_vector_type(8)));
typedef float f32x4 __attribute__((ext_vector_type(4)));

#define MFMA16(a, b, c) __builtin_amdgcn_mfma_f32_16x16x32_bf16((a), (b), (c), 0, 0, 0)

__device__ __forceinline__ short f2bf(float v) {
  __hip_bfloat16 h = __float2bfloat16(v);
  union { __hip_bfloat16 h; short s; } u; u.h = h; return u.s;
}
__device__ __forceinline__ float bf2f(short s) {
  return __uint_as_float(((unsigned int)(unsigned short)s) << 16);
}
// T2-style XOR swizzle: element-col ^ row-bits (granule = 8 shorts = 16 B)
__device__ __forceinline__ int swz(int row, int col) {
  return col ^ ((row & 7) << 3);
}

// ---------------- fused weight prep: dst[n][k] = bf16(src[k][n]) ------------
struct WtAll {
  const float* src[7];
  short* dst[7];
  int K[7], N[7], tile0[7];
};

__global__ __launch_bounds__(256) void k_wt_all(WtAll P) {
  const int bid = blockIdx.x;
  int i = 0;
#pragma unroll
  for (int j = 1; j < 7; j++) if (bid >= P.tile0[j]) i = j;
  const float* src = P.src[i];
  short* dst = P.dst[i];
  const int K = P.K[i], N = P.N[i];
  const int local = bid - P.tile0[i];
  const int ktiles = K >> 5;
  const int nt = local / ktiles, kt = local - nt * ktiles;
  const int k0 = kt * 32, n0 = nt * 32;
  __shared__ float tile[32][33];
  const int tx = threadIdx.x & 31, ty = threadIdx.x >> 5;
#pragma unroll
  for (int r = 0; r < 4; r++)
    tile[ty + r * 8][tx] = src[(size_t)(k0 + ty + r * 8) * N + n0 + tx];
  __syncthreads();
#pragma unroll
  for (int r = 0; r < 4; r++)
    dst[(size_t)(n0 + ty + r * 8) * K + k0 + tx] = f2bf(tile[tx][ty + r * 8]);
}

// ---------------- upsample 2x bilinear align_corners (conflict-free) --------
__global__ __launch_bounds__(256) void k_upsample(const float* __restrict__ x,
                                                  short* __restrict__ xu) {
  __shared__ float ldsV[64][65];
  const int bh = blockIdx.x, z = blockIdx.y;
  const int b = bh >> 7, h = bh & 127;
  const float chf = h * (63.0f / 127.0f);
  int i0 = (int)chf; if (i0 > 62) i0 = 62;
  const float wh = chf - (float)i0;
  const int t = threadIdx.x;
  const int cbase = z * 64;
  const float* xb = x + ((size_t)(b * 256 + cbase) * 64 + i0) * 64;
#pragma unroll
  for (int p = 0; p < 16; p++) {
    const int li = p * 256 + t;
    const int c = li >> 6, w = li & 63;
    const float* px = xb + (size_t)c * 4096 + w;
    const float v0 = px[0], v1 = px[64];
    ldsV[c][w] = v0 * (1.f - wh) + v1 * wh;
  }
  __syncthreads();
  const int cg = t & 7, wi = t >> 3;
  short* xout = xu + (size_t)(bh * 128) * 256 + cbase + cg * 8;
#pragma unroll
  for (int p = 0; p < 4; p++) {
    const int w = p * 32 + wi;
    const float cwf = w * (63.0f / 127.0f);
    int j0 = (int)cwf; if (j0 > 62) j0 = 62;
    const float ww = cwf - (float)j0;
    bf16x8 o;
#pragma unroll
    for (int u = 0; u < 8; u++) {
      const float v0 = ldsV[cg * 8 + u][j0], v1 = ldsV[cg * 8 + u][j0 + 1];
      o[u] = f2bf(v0 * (1.f - ww) + v1 * ww);
    }
    *(bf16x8*)(xout + (size_t)w * 256) = o;
  }
}

// ---------------- fused QKV + attention + proj, one block per sequence ------
// block: 512 threads = 8 waves; wave w owns token rows w*16..w*16+15.
// LDS: Qb (later P), Kb (later O), Vtb — each [128][128] bf16 swizzled. 96 KB.
__global__ __launch_bounds__(512, 2) void k_fused(const short* __restrict__ xu,
                                                  const short* __restrict__ wqkvT,
                                                  const short* __restrict__ woT,
                                                  const float* __restrict__ wob,
                                                  short* __restrict__ accb,
                                                  int dir) {
  __shared__ __align__(16) short Qb[128][128];
  __shared__ __align__(16) short Kb[128][128];
  __shared__ __align__(16) short Vtb[128][128];

  const int s = blockIdx.x;
  const int b = s >> 7, pos = s & 127;
  const int tok0 = b * 16384 + (dir ? pos * 128 : pos);
  const int tstep = dir ? 1 : 128;
  const int tid = threadIdx.x;
  const int lane = tid & 63, wid = tid >> 6;
  const int lr = lane & 15, kb = lane >> 4;
  const float scale = 0.08838834764831845f;  // 128^-0.5

  f32x4 accp[16];
#pragma unroll
  for (int i = 0; i < 16; i++) accp[i] = (f32x4){0.f, 0.f, 0.f, 0.f};

  const short* xrow = xu + (size_t)(tok0 + (wid * 16 + lr) * tstep) * 256 + kb * 8;

  for (int h = 0; h < 2; h++) {
    __syncthreads();  // A: prev head's PV (reads all Vtb) done before re-store

    // ---- Q and K targets: D = xu @ w^T, rows = own 16 tokens ----
#pragma unroll
    for (int t = 0; t < 2; t++) {
      const short* wb = wqkvT + (size_t)(t * 256 + h * 128) * 256 + kb * 8;
      f32x4 a8[8];
#pragma unroll
      for (int i = 0; i < 8; i++) a8[i] = (f32x4){0.f, 0.f, 0.f, 0.f};
#pragma unroll
      for (int ks = 0; ks < 8; ks++) {
        bf16x8 a = *(const bf16x8*)(xrow + ks * 32);
#pragma unroll
        for (int nj = 0; nj < 8; nj++) {
          bf16x8 w = *(const bf16x8*)(wb + (size_t)(nj * 16 + lr) * 256 + ks * 32);
          a8[nj] = MFMA16(a, w, a8[nj]);
        }
      }
      short (*dst)[128] = (t == 0) ? Qb : Kb;
#pragma unroll
      for (int nj = 0; nj < 8; nj++) {
        const int col = nj * 16 + lr;
#pragma unroll
        for (int r = 0; r < 4; r++) {
          const int row = wid * 16 + kb * 4 + r;
          dst[row][swz(row, col)] = f2bf(a8[nj][r]);
        }
      }
    }
    // ---- V target, operand-swapped: D = w @ xu^T = V^T (rows = channels) ----
    {
      const short* wb = wqkvT + (size_t)(512 + h * 128) * 256 + kb * 8;
      f32x4 a8[8];
#pragma unroll
      for (int i = 0; i < 8; i++) a8[i] = (f32x4){0.f, 0.f, 0.f, 0.f};
#pragma unroll
      for (int ks = 0; ks < 8; ks++) {
        bf16x8 a = *(const bf16x8*)(xrow + ks * 32);
#pragma unroll
        for (int mi = 0; mi < 8; mi++) {
          bf16x8 w = *(const bf16x8*)(wb + (size_t)(mi * 16 + lr) * 256 + ks * 32);
          a8[mi] = MFMA16(w, a, a8[mi]);
        }
      }
      const int col = wid * 16 + lr;  // own token as column
#pragma unroll
      for (int mi = 0; mi < 8; mi++) {
#pragma unroll
        for (int r = 0; r < 4; r++) {
          const int row = mi * 16 + kb * 4 + r;  // channel
          Vtb[row][swz(row, col)] = f2bf(a8[mi][r]);
        }
      }
    }

    __syncthreads();  // B: Q/K/Vt visible to all waves

    // ---- S = Q K^T : rows = own tokens, cols = keys ----
    f32x4 s8[8];
#pragma unroll
    for (int i = 0; i < 8; i++) s8[i] = (f32x4){0.f, 0.f, 0.f, 0.f};
#pragma unroll
    for (int ks = 0; ks < 4; ks++) {
      const int qrow = wid * 16 + lr;
      bf16x8 aq = *(const bf16x8*)&Qb[qrow][swz(qrow, ks * 32 + kb * 8)];
#pragma unroll
      for (int nj = 0; nj < 8; nj++) {
        const int krow = nj * 16 + lr;
        bf16x8 bk = *(const bf16x8*)&Kb[krow][swz(krow, ks * 32 + kb * 8)];
        s8[nj] = MFMA16(aq, bk, s8[nj]);
      }
    }
    // ---- softmax over keys; P overwrites Qb ----
#pragma unroll
    for (int rr = 0; rr < 4; rr++) {
      float m = s8[0][rr];
#pragma unroll
      for (int nj = 1; nj < 8; nj++) m = fmaxf(m, s8[nj][rr]);
      m = fmaxf(m, __shfl_xor(m, 1)); m = fmaxf(m, __shfl_xor(m, 2));
      m = fmaxf(m, __shfl_xor(m, 4)); m = fmaxf(m, __shfl_xor(m, 8));
      float p[8], sum = 0.f;
#pragma unroll
      for (int nj = 0; nj < 8; nj++) { p[nj] = __expf((s8[nj][rr] - m) * scale); sum += p[nj]; }
      sum += __shfl_xor(sum, 1); sum += __shfl_xor(sum, 2);
      sum += __shfl_xor(sum, 4); sum += __shfl_xor(sum, 8);
      const float inv = 1.f / sum;
      const int row = wid * 16 + kb * 4 + rr;
#pragma unroll
      for (int nj = 0; nj < 8; nj++)
        Qb[row][swz(row, nj * 16 + lr)] = f2bf(p[nj] * inv);
    }

    __syncthreads();  // C: all QK^T reads of Kb done before O overwrites it

    // ---- O = P V : rows = own tokens, cols = channels ----
    f32x4 o8[8];
#pragma unroll
    for (int i = 0; i < 8; i++) o8[i] = (f32x4){0.f, 0.f, 0.f, 0.f};
#pragma unroll
    for (int ks = 0; ks < 4; ks++) {
      const int prow = wid * 16 + lr;
      bf16x8 ap = *(const bf16x8*)&Qb[prow][swz(prow, ks * 32 + kb * 8)];
#pragma unroll
      for (int nj = 0; nj < 8; nj++) {
        const int vrow = nj * 16 + lr;
        bf16x8 bv = *(const bf16x8*)&Vtb[vrow][swz(vrow, ks * 32 + kb * 8)];
        o8[nj] = MFMA16(ap, bv, o8[nj]);
      }
    }
    // O -> Kb (own rows; within-wave reuse)
#pragma unroll
    for (int nj = 0; nj < 8; nj++) {
      const int col = nj * 16 + lr;
#pragma unroll
      for (int r = 0; r < 4; r++) {
        const int row = wid * 16 + kb * 4 + r;
        Kb[row][swz(row, col)] = f2bf(o8[nj][r]);
      }
    }
    // ---- proj partial: accp += O_h @ wo[h*128:(h+1)*128, :] ----
#pragma unroll
    for (int ks = 0; ks < 4; ks++) {
      const int orow = wid * 16 + lr;
      bf16x8 ao = *(const bf16x8*)&Kb[orow][swz(orow, ks * 32 + kb * 8)];
#pragma unroll
      for (int nj = 0; nj < 16; nj++) {
        bf16x8 bw = *(const bf16x8*)(woT + (size_t)(nj * 16 + lr) * 256 +
                                     h * 128 + ks * 32 + kb * 8);
        accp[nj] = MFMA16(ao, bw, accp[nj]);
      }
    }
  }

  // ---- write accb (+ bias, + previous direction) ----
#pragma unroll
  for (int nj = 0; nj < 16; nj++) {
    const int c = nj * 16 + lr;
    const float bb = wob[c];
#pragma unroll
    for (int r = 0; r < 4; r++) {
      const int row = wid * 16 + kb * 4 + r;
      const size_t idx = (size_t)(tok0 + row * tstep) * 256 + c;
      float v = accp[nj][r] + bb;
      if (dir) v += bf2f(accb[idx]);
      accb[idx] = f2bf(v);
    }
  }
}

// ---------------- conv1x1: [relu(accb)|xu|res] @ convT^T -> relu -> ytmp ----
__global__ __launch_bounds__(256) void k_gemm_conv(const short* __restrict__ accb,
                                                   const short* __restrict__ xu,
                                                   const float* __restrict__ res,
                                                   const short* __restrict__ Bt,
                                                   float* __restrict__ ytmp) {
  const int tid = threadIdx.x;
  const int lane = tid & 63, wid = tid >> 6;
  const int lr = lane & 15, kb = lane >> 4;
  const int wr = wid >> 1, wc = wid & 1;
  const int m0 = blockIdx.y * 128;
  f32x4 acc[4][4];
#pragma unroll
  for (int i = 0; i < 4; i++)
#pragma unroll
    for (int j = 0; j < 4; j++) acc[i][j] = (f32x4){0.f, 0.f, 0.f, 0.f};
  const short* arow1 = accb + (size_t)(m0 + wr * 64 + lr) * 256 + kb * 8;
  const short* arow2 = xu + (size_t)(m0 + wr * 64 + lr) * 256 + kb * 8;
  const short* brow = Bt + (size_t)(wc * 64 + lr) * 640 + kb * 8;
#pragma unroll
  for (int ks = 0; ks < 8; ks++) {
    bf16x8 a[4], b[4];
#pragma unroll
    for (int mi = 0; mi < 4; mi++) {
      bf16x8 tv = *(const bf16x8*)(arow1 + (size_t)mi * 16 * 256 + ks * 32);
#pragma unroll
      for (int u = 0; u < 8; u++)
        tv[u] = ((unsigned short)tv[u] & 0x8000u) ? (short)0 : tv[u];
      a[mi] = tv;
    }
#pragma unroll
    for (int nj = 0; nj < 4; nj++)
      b[nj] = *(const bf16x8*)(brow + (size_t)nj * 16 * 640 + ks * 32);
#pragma unroll
    for (int mi = 0; mi < 4; mi++)
#pragma unroll
      for (int nj = 0; nj < 4; nj++)
        acc[mi][nj] = MFMA16(a[mi], b[nj], acc[mi][nj]);
  }
#pragma unroll
  for (int ks = 8; ks < 16; ks++) {
    bf16x8 a[4], b[4];
#pragma unroll
    for (int mi = 0; mi < 4; mi++)
      a[mi] = *(const bf16x8*)(arow2 + (size_t)mi * 16 * 256 + (ks - 8) * 32);
#pragma unroll
    for (int nj = 0; nj < 4; nj++)
      b[nj] = *(const bf16x8*)(brow + (size_t)nj * 16 * 640 + ks * 32);
#pragma unroll
    for (int mi = 0; mi < 4; mi++)
#pragma unroll
      for (int nj = 0; nj < 4; nj++)
        acc[mi][nj] = MFMA16(a[mi], b[nj], acc[mi][nj]);
  }
  const int bC = (m0 >> 14) * 128;
  const int hh = (m0 >> 7) & 127;
#pragma unroll
  for (int ks = 16; ks < 20; ks++) {
    const int e0 = (ks - 16) * 32 + kb * 8;
    bf16x8 a[4], b[4];
#pragma unroll
    for (int mi = 0; mi < 4; mi++) {
      const int wl = wr * 64 + mi * 16 + lr;
      const float* rp = res + ((size_t)(bC + e0) * 128 + hh) * 128 + wl;
      bf16x8 tv;
#pragma unroll
      for (int u = 0; u < 8; u++) tv[u] = f2bf(rp[(size_t)u * 16384]);
      a[mi] = tv;
    }
#pragma unroll
    for (int nj = 0; nj < 4; nj++)
      b[nj] = *(const bf16x8*)(brow + (size_t)nj * 16 * 640 + ks * 32);
#pragma unroll
    for (int mi = 0; mi < 4; mi++)
#pragma unroll
      for (int nj = 0; nj < 4; nj++)
        acc[mi][nj] = MFMA16(a[mi], b[nj], acc[mi][nj]);
  }
#pragma unroll
  for (int mi = 0; mi < 4; mi++) {
    const int rbase = m0 + wr * 64 + mi * 16 + kb * 4;
#pragma unroll
    for (int nj = 0; nj < 4; nj++) {
      const int c = wc * 64 + nj * 16 + lr;
#pragma unroll
      for (int r = 0; r < 4; r++)
        ytmp[(size_t)(rbase + r) * 128 + c] = fmaxf(acc[mi][nj][r], 0.f);
    }
  }
}

// ---------------- BN stats pass 1 ----------------
__global__ __launch_bounds__(256) void k_bnstats1(const float* __restrict__ y,
                                                  float* __restrict__ partial) {
  const int blk = blockIdx.x, tid = threadIdx.x;
  const int ch = tid & 127, sub = tid >> 7;
  float s = 0.f, s2 = 0.f;
  const float* p = y + (size_t)(blk * 512 + sub) * 128 + ch;
  for (int i = 0; i < 256; i++) {
    float v = p[(size_t)i * 256];
    s += v; s2 += v * v;
  }
  __shared__ float rs[2][128], rs2[2][128];
  rs[sub][ch] = s; rs2[sub][ch] = s2;
  __syncthreads();
  if (tid < 128) {
    partial[(size_t)(blk * 128 + tid) * 2]     = rs[0][tid] + rs[1][tid];
    partial[(size_t)(blk * 128 + tid) * 2 + 1] = rs2[0][tid] + rs2[1][tid];
  }
}

// ---------------- BN stats pass 2 ----------------
__global__ __launch_bounds__(128) void k_bnstats2(const float* __restrict__ partial,
                                                  float* __restrict__ stats) {
  const int ch = threadIdx.x;
  float s = 0.f, s2 = 0.f;
  for (int i = 0; i < 128; i++) {
    s  += partial[(size_t)(i * 128 + ch) * 2];
    s2 += partial[(size_t)(i * 128 + ch) * 2 + 1];
  }
  const float mu = s * (1.f / 65536.f);
  const float var = s2 * (1.f / 65536.f) - mu * mu;
  stats[ch * 2] = mu;
  stats[ch * 2 + 1] = rsqrtf(var + 1e-5f);
}

// ---------------- BN apply + transpose to (B,E,H,W) ----------------
__global__ __launch_bounds__(256) void k_bnout(const float* __restrict__ y,
                                               const float* __restrict__ stats,
                                               const float* __restrict__ gamma,
                                               const float* __restrict__ beta,
                                               float* __restrict__ out) {
  const int bh = blockIdx.x;
  const int b = bh >> 7, h = bh & 127;
  const int w = threadIdx.x & 127, eh = threadIdx.x >> 7;
  const float* yp = y + (size_t)(bh * 128 + w) * 128;
  for (int e2 = 0; e2 < 64; e2++) {
    const int e = e2 * 2 + eh;
    const float mu = stats[e * 2], rstd = stats[e * 2 + 1];
    const float v = yp[e];
    out[((size_t)(b * 128 + e) << 14) + h * 128 + w] =
        (v - mu) * rstd * gamma[e] + beta[e];
  }
}

// ---------------- launcher ----------------
extern "C" void kernel_launch(void* const* d_in, const int* in_sizes, int n_in,
                              void* d_out, int out_size, void* d_ws, size_t ws_size,
                              hipStream_t stream) {
  const float* x      = (const float*)d_in[0];
  const float* res    = (const float*)d_in[1];
  const float* wq_h   = (const float*)d_in[2];
  const float* wkv_h  = (const float*)d_in[3];
  const float* wo_h   = (const float*)d_in[4];
  const float* wob_h  = (const float*)d_in[5];
  const float* wq_w   = (const float*)d_in[6];
  const float* wkv_w  = (const float*)d_in[7];
  const float* wo_w   = (const float*)d_in[8];
  const float* wob_w  = (const float*)d_in[9];
  const float* conv_w = (const float*)d_in[10];
  const float* gamma  = (const float*)d_in[11];
  const float* beta   = (const float*)d_in[12];

  char* ws = (char*)d_ws;
  short* wqkvT[2] = {(short*)(ws + 0), (short*)(ws + 393216)};
  short* woT[2]   = {(short*)(ws + 786432), (short*)(ws + 917504)};
  short* convT    = (short*)(ws + 1048576);
  short* xu       = (short*)(ws + 1245184);
  float* ytmp     = (float*)(ws + 34799616);
  float* partial  = (float*)(ws + 68354048);
  float* stats    = (float*)(ws + 68485120);
  short* accb     = (short*)d_out;             // axial sum scratch in d_out
  float* out      = (float*)d_out;

  if (ws_size < 68486144ull)
    fprintf(stderr, "kernel_launch: ws_size %zu too small\n", ws_size);

  // fused weight prep: starts 0,64,192,256,384,448,512; total 592 tiles
  WtAll P;
  P.src[0] = wq_h;  P.dst[0] = wqkvT[0];          P.K[0] = 256; P.N[0] = 256; P.tile0[0] = 0;
  P.src[1] = wkv_h; P.dst[1] = wqkvT[0] + 65536;  P.K[1] = 256; P.N[1] = 512; P.tile0[1] = 64;
  P.src[2] = wq_w;  P.dst[2] = wqkvT[1];          P.K[2] = 256; P.N[2] = 256; P.tile0[2] = 192;
  P.src[3] = wkv_w; P.dst[3] = wqkvT[1] + 65536;  P.K[3] = 256; P.N[3] = 512; P.tile0[3] = 256;
  P.src[4] = wo_h;  P.dst[4] = woT[0];            P.K[4] = 256; P.N[4] = 256; P.tile0[4] = 384;
  P.src[5] = wo_w;  P.dst[5] = woT[1];            P.K[5] = 256; P.N[5] = 256; P.tile0[5] = 448;
  P.src[6] = conv_w;P.dst[6] = convT;             P.K[6] = 640; P.N[6] = 128; P.tile0[6] = 512;
  k_wt_all<<<592, 256, 0, stream>>>(P);

  k_upsample<<<dim3(512, 4), 256, 0, stream>>>(x, xu);

  k_fused<<<512, 512, 0, stream>>>(xu, wqkvT[0], woT[0], wob_h, accb, 0);
  k_fused<<<512, 512, 0, stream>>>(xu, wqkvT[1], woT[1], wob_w, accb, 1);

  k_gemm_conv<<<dim3(1, 512), 256, 0, stream>>>(accb, xu, res, convT, ytmp);
  k_bnstats1<<<128, 256, 0, stream>>>(ytmp, partial);
  k_bnstats2<<<1, 128, 0, stream>>>(partial, stats);
  k_bnout<<<512, 256, 0, stream>>>(ytmp, stats, gamma, beta, out);
}

// Round 5
// 270.849 us; speedup vs baseline: 2.6415x; 2.6415x over previous
//
#include <hip/hip_runtime.h>
#include <hip/hip_bf16.h>
#include <cstdio>

// BlockAxialUp on MI355X, round 5: fused QKV+attn+proj rebuilt.
// Round-4 failure: 256 serialized L2 weight loads/wave/head + dir-0 gather.
// Now: x-tile staged in LDS (coalesced, swizzled); QKV production and proj
// split by out-channel across waves (weights: 32 batched loads/wave/head);
// swapped-operand MFMA so every LDS/global epilogue write is packed.
//
// ws layout (bytes):
//   0        wqkvT_h bf16 [768][256]  (rows: q 0:256, k 256:512, v 512:768)
//   393216   wqkvT_w
//   786432   woT_h  bf16 [256][256]
//   917504   woT_w
//   1048576  convT  bf16 [128][640]
//   1245184  xu     bf16 [65536][256]
//   34799616 ytmp   f32  [65536][128]
//   68354048 partial f32 [128][128][2]
//   68485120 stats  f32  [128][2]
// accb (ah+aw, bf16 [65536][256]) lives in d_out; final f32 overwrites it.

typedef short bf16x8 __attribute__((ext_vector_type(8)));
typedef short bf16x4 __attribute__((ext_vector_type(4)));
typedef float f32x4 __attribute__((ext_vector_type(4)));

#define MFMA16(a, b, c) __builtin_amdgcn_mfma_f32_16x16x32_bf16((a), (b), (c), 0, 0, 0)

__device__ __forceinline__ short f2bf(float v) {
  __hip_bfloat16 h = __float2bfloat16(v);
  union { __hip_bfloat16 h; short s; } u; u.h = h; return u.s;
}
__device__ __forceinline__ float bf2f(short s) {
  return __uint_as_float(((unsigned int)(unsigned short)s) << 16);
}
// XOR swizzle, granule = 8 shorts (16 B): spreads strided row reads over banks
__device__ __forceinline__ int swz(int row, int col) {
  return col ^ ((row & 7) << 3);
}

// ---------------- fused weight prep: dst[n][k] = bf16(src[k][n]) ------------
struct WtAll {
  const float* src[7];
  short* dst[7];
  int K[7], N[7], tile0[7];
};

__global__ __launch_bounds__(256) void k_wt_all(WtAll P) {
  const int bid = blockIdx.x;
  int i = 0;
#pragma unroll
  for (int j = 1; j < 7; j++) if (bid >= P.tile0[j]) i = j;
  const float* src = P.src[i];
  short* dst = P.dst[i];
  const int K = P.K[i], N = P.N[i];
  const int local = bid - P.tile0[i];
  const int ktiles = K >> 5;
  const int nt = local / ktiles, kt = local - nt * ktiles;
  const int k0 = kt * 32, n0 = nt * 32;
  __shared__ float tile[32][33];
  const int tx = threadIdx.x & 31, ty = threadIdx.x >> 5;
#pragma unroll
  for (int r = 0; r < 4; r++)
    tile[ty + r * 8][tx] = src[(size_t)(k0 + ty + r * 8) * N + n0 + tx];
  __syncthreads();
#pragma unroll
  for (int r = 0; r < 4; r++)
    dst[(size_t)(n0 + ty + r * 8) * K + k0 + tx] = f2bf(tile[tx][ty + r * 8]);
}

// ---------------- upsample 2x bilinear align_corners (conflict-free) --------
__global__ __launch_bounds__(256) void k_upsample(const float* __restrict__ x,
                                                  short* __restrict__ xu) {
  __shared__ float ldsV[64][65];
  const int bh = blockIdx.x, z = blockIdx.y;
  const int b = bh >> 7, h = bh & 127;
  const float chf = h * (63.0f / 127.0f);
  int i0 = (int)chf; if (i0 > 62) i0 = 62;
  const float wh = chf - (float)i0;
  const int t = threadIdx.x;
  const int cbase = z * 64;
  const float* xb = x + ((size_t)(b * 256 + cbase) * 64 + i0) * 64;
#pragma unroll
  for (int p = 0; p < 16; p++) {
    const int li = p * 256 + t;
    const int c = li >> 6, w = li & 63;
    const float* px = xb + (size_t)c * 4096 + w;
    const float v0 = px[0], v1 = px[64];
    ldsV[c][w] = v0 * (1.f - wh) + v1 * wh;
  }
  __syncthreads();
  const int cg = t & 7, wi = t >> 3;
  short* xout = xu + (size_t)(bh * 128) * 256 + cbase + cg * 8;
#pragma unroll
  for (int p = 0; p < 4; p++) {
    const int w = p * 32 + wi;
    const float cwf = w * (63.0f / 127.0f);
    int j0 = (int)cwf; if (j0 > 62) j0 = 62;
    const float ww = cwf - (float)j0;
    bf16x8 o;
#pragma unroll
    for (int u = 0; u < 8; u++) {
      const float v0 = ldsV[cg * 8 + u][j0], v1 = ldsV[cg * 8 + u][j0 + 1];
      o[u] = f2bf(v0 * (1.f - ww) + v1 * ww);
    }
    *(bf16x8*)(xout + (size_t)w * 256) = o;
  }
}

// ---------------- fused QKV + attention + proj, one block per sequence ------
// 512 thr = 8 waves. Production/proj: wave w owns out-chan tile(s);
// S/softmax/PV: wave w owns token rows w*16..+15.
// LDS: Xs 64K + Qb(P) 32K + Kb(O) 32K + Vtb 32K = 160 KB.
__global__ __launch_bounds__(512, 2) void k_fused(const short* __restrict__ xu,
                                                  const short* __restrict__ wqkvT,
                                                  const short* __restrict__ woT,
                                                  const float* __restrict__ wob,
                                                  short* __restrict__ accb,
                                                  int dir) {
  __shared__ __align__(16) short Xs[128][256];
  __shared__ __align__(16) short Qb[128][128];
  __shared__ __align__(16) short Kb[128][128];
  __shared__ __align__(16) short Vtb[128][128];

  const int s = blockIdx.x;
  const int b = s >> 7, pos = s & 127;
  const int tok0 = b * 16384 + (dir ? pos * 128 : pos);
  const int tstep = dir ? 1 : 128;
  const int tid = threadIdx.x;
  const int lane = tid & 63, wid = tid >> 6;
  const int lr = lane & 15, kb = lane >> 4;
  const int ct = wid * 16;                 // wave's chan tile / token tile base
  const float scale = 0.08838834764831845f;  // 128^-0.5

  // ---- stage Xs: coalesced (32 lanes cover one 512 B token row) ----
#pragma unroll
  for (int p = 0; p < 8; p++) {
    const int u = p * 512 + tid;
    const int row = u >> 5, ck = (u & 31) * 8;
    bf16x8 v = *(const bf16x8*)(xu + (size_t)(tok0 + row * tstep) * 256 + ck);
    *(bf16x8*)&Xs[row][swz(row, ck)] = v;
  }

  f32x4 accp[2][8];
#pragma unroll
  for (int i = 0; i < 2; i++)
#pragma unroll
    for (int j = 0; j < 8; j++) accp[i][j] = (f32x4){0.f, 0.f, 0.f, 0.f};

  for (int h = 0; h < 2; h++) {
    __syncthreads();  // A: Xs staged (h=0) / prev head's LDS reads done

    // ---- produce Q,K for chans ct..ct+15 (all 128 tokens) ----
    {
      const short* wqb = wqkvT + (size_t)(h * 128 + ct + lr) * 256 + kb * 8;
      const short* wkb = wqkvT + (size_t)(256 + h * 128 + ct + lr) * 256 + kb * 8;
      bf16x8 wq[8], wk[8];
#pragma unroll
      for (int ks = 0; ks < 8; ks++) {
        wq[ks] = *(const bf16x8*)(wqb + ks * 32);
        wk[ks] = *(const bf16x8*)(wkb + ks * 32);
      }
#pragma unroll
      for (int nt = 0; nt < 8; nt++) {
        const int xrow = nt * 16 + lr;
        f32x4 dq = (f32x4){0.f, 0.f, 0.f, 0.f};
        f32x4 dk = (f32x4){0.f, 0.f, 0.f, 0.f};
#pragma unroll
        for (int ks = 0; ks < 8; ks++) {
          bf16x8 xf = *(const bf16x8*)&Xs[xrow][swz(xrow, kb * 8 + ks * 32)];
          dq = MFMA16(wq[ks], xf, dq);
          dk = MFMA16(wk[ks], xf, dk);
        }
        // D[m=chan ct+kb*4+r][n=token nt*16+lr] -> packed row writes
        const int trow = nt * 16 + lr, cc = ct + kb * 4;
        bf16x4 pq = {f2bf(dq[0]), f2bf(dq[1]), f2bf(dq[2]), f2bf(dq[3])};
        bf16x4 pk = {f2bf(dk[0]), f2bf(dk[1]), f2bf(dk[2]), f2bf(dk[3])};
        *(bf16x4*)&Qb[trow][swz(trow, cc)] = pq;
        *(bf16x4*)&Kb[trow][swz(trow, cc)] = pk;
      }
    }
    // ---- produce V^T for chans ct..ct+15 ----
    {
      const short* wvb = wqkvT + (size_t)(512 + h * 128 + ct + lr) * 256 + kb * 8;
      bf16x8 wv[8];
#pragma unroll
      for (int ks = 0; ks < 8; ks++) wv[ks] = *(const bf16x8*)(wvb + ks * 32);
#pragma unroll
      for (int nt = 0; nt < 8; nt++) {
        const int xrow = nt * 16 + lr;
        f32x4 dv = (f32x4){0.f, 0.f, 0.f, 0.f};
#pragma unroll
        for (int ks = 0; ks < 8; ks++) {
          bf16x8 xf = *(const bf16x8*)&Xs[xrow][swz(xrow, kb * 8 + ks * 32)];
          dv = MFMA16(wv[ks], xf, dv);
        }
        const int col = nt * 16 + lr;
#pragma unroll
        for (int r = 0; r < 4; r++) {
          const int vrow = ct + kb * 4 + r;
          Vtb[vrow][swz(vrow, col)] = f2bf(dv[r]);
        }
      }
    }

    __syncthreads();  // B: Q/K/Vt visible

    // ---- S = Q K^T for q-tokens ct..ct+15 ----
    f32x4 s8[8];
#pragma unroll
    for (int i = 0; i < 8; i++) s8[i] = (f32x4){0.f, 0.f, 0.f, 0.f};
    const int qrow = ct + lr;
#pragma unroll
    for (int ks = 0; ks < 4; ks++) {
      bf16x8 aq = *(const bf16x8*)&Qb[qrow][swz(qrow, kb * 8 + ks * 32)];
#pragma unroll
      for (int nj = 0; nj < 8; nj++) {
        const int krow = nj * 16 + lr;
        bf16x8 bk = *(const bf16x8*)&Kb[krow][swz(krow, kb * 8 + ks * 32)];
        s8[nj] = MFMA16(aq, bk, s8[nj]);
      }
    }
    // ---- softmax rows ct+kb*4+r; P overwrites own Qb rows ----
#pragma unroll
    for (int rr = 0; rr < 4; rr++) {
      float m = s8[0][rr];
#pragma unroll
      for (int nj = 1; nj < 8; nj++) m = fmaxf(m, s8[nj][rr]);
      m = fmaxf(m, __shfl_xor(m, 1)); m = fmaxf(m, __shfl_xor(m, 2));
      m = fmaxf(m, __shfl_xor(m, 4)); m = fmaxf(m, __shfl_xor(m, 8));
      float p[8], sum = 0.f;
#pragma unroll
      for (int nj = 0; nj < 8; nj++) { p[nj] = __expf((s8[nj][rr] - m) * scale); sum += p[nj]; }
      sum += __shfl_xor(sum, 1); sum += __shfl_xor(sum, 2);
      sum += __shfl_xor(sum, 4); sum += __shfl_xor(sum, 8);
      const float inv = 1.f / sum;
      const int prow = ct + kb * 4 + rr;
#pragma unroll
      for (int nj = 0; nj < 8; nj++)
        Qb[prow][swz(prow, nj * 16 + lr)] = f2bf(p[nj] * inv);
    }

    __syncthreads();  // C: all S reads of Kb done; O may overwrite

    // ---- O = P V for own tokens; packed into own Kb rows ----
    f32x4 o8[8];
#pragma unroll
    for (int i = 0; i < 8; i++) o8[i] = (f32x4){0.f, 0.f, 0.f, 0.f};
#pragma unroll
    for (int ks = 0; ks < 4; ks++) {
      bf16x8 bp = *(const bf16x8*)&Qb[qrow][swz(qrow, kb * 8 + ks * 32)];
#pragma unroll
      for (int mi = 0; mi < 8; mi++) {
        const int vrow = mi * 16 + lr;
        bf16x8 av = *(const bf16x8*)&Vtb[vrow][swz(vrow, kb * 8 + ks * 32)];
        o8[mi] = MFMA16(av, bp, o8[mi]);
      }
    }
    const int orow = ct + lr;
#pragma unroll
    for (int mi = 0; mi < 8; mi++) {
      const int cc = mi * 16 + kb * 4;
      bf16x4 po = {f2bf(o8[mi][0]), f2bf(o8[mi][1]), f2bf(o8[mi][2]), f2bf(o8[mi][3])};
      *(bf16x4*)&Kb[orow][swz(orow, cc)] = po;
    }

    __syncthreads();  // D: O complete for all waves

    // ---- proj: out-chans [wid*32, wid*32+32), all tokens ----
    {
      const short* w0 = woT + (size_t)(wid * 32 + lr) * 256 + h * 128 + kb * 8;
      const short* w1 = woT + (size_t)(wid * 32 + 16 + lr) * 256 + h * 128 + kb * 8;
      bf16x8 wa[4], wb[4];
#pragma unroll
      for (int ks = 0; ks < 4; ks++) {
        wa[ks] = *(const bf16x8*)(w0 + ks * 32);
        wb[ks] = *(const bf16x8*)(w1 + ks * 32);
      }
#pragma unroll
      for (int nt = 0; nt < 8; nt++) {
        const int trow = nt * 16 + lr;
#pragma unroll
        for (int ks = 0; ks < 4; ks++) {
          bf16x8 bo = *(const bf16x8*)&Kb[trow][swz(trow, kb * 8 + ks * 32)];
          accp[0][nt] = MFMA16(wa[ks], bo, accp[0][nt]);
          accp[1][nt] = MFMA16(wb[ks], bo, accp[1][nt]);
        }
      }
    }
  }

  // ---- accb write: token = nt*16+lr, outc = wid*32 + mi2*16 + kb*4 + r ----
#pragma unroll
  for (int mi2 = 0; mi2 < 2; mi2++) {
    const int outc = wid * 32 + mi2 * 16 + kb * 4;
    const float b0 = wob[outc], b1 = wob[outc + 1];
    const float b2 = wob[outc + 2], b3 = wob[outc + 3];
#pragma unroll
    for (int nt = 0; nt < 8; nt++) {
      const int token = tok0 + (nt * 16 + lr) * tstep;
      short* op = accb + (size_t)token * 256 + outc;
      float v0 = accp[mi2][nt][0] + b0, v1 = accp[mi2][nt][1] + b1;
      float v2 = accp[mi2][nt][2] + b2, v3 = accp[mi2][nt][3] + b3;
      if (dir) {
        bf16x4 old = *(const bf16x4*)op;
        v0 += bf2f(old[0]); v1 += bf2f(old[1]);
        v2 += bf2f(old[2]); v3 += bf2f(old[3]);
      }
      bf16x4 pv = {f2bf(v0), f2bf(v1), f2bf(v2), f2bf(v3)};
      *(bf16x4*)op = pv;
    }
  }
}

// ---------------- conv1x1: [relu(accb)|xu|res] @ convT^T -> relu -> ytmp ----
__global__ __launch_bounds__(256) void k_gemm_conv(const short* __restrict__ accb,
                                                   const short* __restrict__ xu,
                                                   const float* __restrict__ res,
                                                   const short* __restrict__ Bt,
                                                   float* __restrict__ ytmp) {
  const int tid = threadIdx.x;
  const int lane = tid & 63, wid = tid >> 6;
  const int lr = lane & 15, kb = lane >> 4;
  const int wr = wid >> 1, wc = wid & 1;
  const int m0 = blockIdx.y * 128;
  f32x4 acc[4][4];
#pragma unroll
  for (int i = 0; i < 4; i++)
#pragma unroll
    for (int j = 0; j < 4; j++) acc[i][j] = (f32x4){0.f, 0.f, 0.f, 0.f};
  const short* arow1 = accb + (size_t)(m0 + wr * 64 + lr) * 256 + kb * 8;
  const short* arow2 = xu + (size_t)(m0 + wr * 64 + lr) * 256 + kb * 8;
  const short* brow = Bt + (size_t)(wc * 64 + lr) * 640 + kb * 8;
#pragma unroll
  for (int ks = 0; ks < 8; ks++) {
    bf16x8 a[4], b[4];
#pragma unroll
    for (int mi = 0; mi < 4; mi++) {
      bf16x8 tv = *(const bf16x8*)(arow1 + (size_t)mi * 16 * 256 + ks * 32);
#pragma unroll
      for (int u = 0; u < 8; u++)
        tv[u] = ((unsigned short)tv[u] & 0x8000u) ? (short)0 : tv[u];
      a[mi] = tv;
    }
#pragma unroll
    for (int nj = 0; nj < 4; nj++)
      b[nj] = *(const bf16x8*)(brow + (size_t)nj * 16 * 640 + ks * 32);
#pragma unroll
    for (int mi = 0; mi < 4; mi++)
#pragma unroll
      for (int nj = 0; nj < 4; nj++)
        acc[mi][nj] = MFMA16(a[mi], b[nj], acc[mi][nj]);
  }
#pragma unroll
  for (int ks = 8; ks < 16; ks++) {
    bf16x8 a[4], b[4];
#pragma unroll
    for (int mi = 0; mi < 4; mi++)
      a[mi] = *(const bf16x8*)(arow2 + (size_t)mi * 16 * 256 + (ks - 8) * 32);
#pragma unroll
    for (int nj = 0; nj < 4; nj++)
      b[nj] = *(const bf16x8*)(brow + (size_t)nj * 16 * 640 + ks * 32);
#pragma unroll
    for (int mi = 0; mi < 4; mi++)
#pragma unroll
      for (int nj = 0; nj < 4; nj++)
        acc[mi][nj] = MFMA16(a[mi], b[nj], acc[mi][nj]);
  }
  const int bC = (m0 >> 14) * 128;
  const int hh = (m0 >> 7) & 127;
#pragma unroll
  for (int ks = 16; ks < 20; ks++) {
    const int e0 = (ks - 16) * 32 + kb * 8;
    bf16x8 a[4], b[4];
#pragma unroll
    for (int mi = 0; mi < 4; mi++) {
      const int wl = wr * 64 + mi * 16 + lr;
      const float* rp = res + ((size_t)(bC + e0) * 128 + hh) * 128 + wl;
      bf16x8 tv;
#pragma unroll
      for (int u = 0; u < 8; u++) tv[u] = f2bf(rp[(size_t)u * 16384]);
      a[mi] = tv;
    }
#pragma unroll
    for (int nj = 0; nj < 4; nj++)
      b[nj] = *(const bf16x8*)(brow + (size_t)nj * 16 * 640 + ks * 32);
#pragma unroll
    for (int mi = 0; mi < 4; mi++)
#pragma unroll
      for (int nj = 0; nj < 4; nj++)
        acc[mi][nj] = MFMA16(a[mi], b[nj], acc[mi][nj]);
  }
#pragma unroll
  for (int mi = 0; mi < 4; mi++) {
    const int rbase = m0 + wr * 64 + mi * 16 + kb * 4;
#pragma unroll
    for (int nj = 0; nj < 4; nj++) {
      const int c = wc * 64 + nj * 16 + lr;
#pragma unroll
      for (int r = 0; r < 4; r++)
        ytmp[(size_t)(rbase + r) * 128 + c] = fmaxf(acc[mi][nj][r], 0.f);
    }
  }
}

// ---------------- BN stats pass 1 ----------------
__global__ __launch_bounds__(256) void k_bnstats1(const float* __restrict__ y,
                                                  float* __restrict__ partial) {
  const int blk = blockIdx.x, tid = threadIdx.x;
  const int ch = tid & 127, sub = tid >> 7;
  float s = 0.f, s2 = 0.f;
  const float* p = y + (size_t)(blk * 512 + sub) * 128 + ch;
  for (int i = 0; i < 256; i++) {
    float v = p[(size_t)i * 256];
    s += v; s2 += v * v;
  }
  __shared__ float rs[2][128], rs2[2][128];
  rs[sub][ch] = s; rs2[sub][ch] = s2;
  __syncthreads();
  if (tid < 128) {
    partial[(size_t)(blk * 128 + tid) * 2]     = rs[0][tid] + rs[1][tid];
    partial[(size_t)(blk * 128 + tid) * 2 + 1] = rs2[0][tid] + rs2[1][tid];
  }
}

// ---------------- BN stats pass 2 ----------------
__global__ __launch_bounds__(128) void k_bnstats2(const float* __restrict__ partial,
                                                  float* __restrict__ stats) {
  const int ch = threadIdx.x;
  float s = 0.f, s2 = 0.f;
  for (int i = 0; i < 128; i++) {
    s  += partial[(size_t)(i * 128 + ch) * 2];
    s2 += partial[(size_t)(i * 128 + ch) * 2 + 1];
  }
  const float mu = s * (1.f / 65536.f);
  const float var = s2 * (1.f / 65536.f) - mu * mu;
  stats[ch * 2] = mu;
  stats[ch * 2 + 1] = rsqrtf(var + 1e-5f);
}

// ---------------- BN apply + transpose to (B,E,H,W) ----------------
__global__ __launch_bounds__(256) void k_bnout(const float* __restrict__ y,
                                               const float* __restrict__ stats,
                                               const float* __restrict__ gamma,
                                               const float* __restrict__ beta,
                                               float* __restrict__ out) {
  const int bh = blockIdx.x;
  const int b = bh >> 7, h = bh & 127;
  const int w = threadIdx.x & 127, eh = threadIdx.x >> 7;
  const float* yp = y + (size_t)(bh * 128 + w) * 128;
  for (int e2 = 0; e2 < 64; e2++) {
    const int e = e2 * 2 + eh;
    const float mu = stats[e * 2], rstd = stats[e * 2 + 1];
    const float v = yp[e];
    out[((size_t)(b * 128 + e) << 14) + h * 128 + w] =
        (v - mu) * rstd * gamma[e] + beta[e];
  }
}

// ---------------- launcher ----------------
extern "C" void kernel_launch(void* const* d_in, const int* in_sizes, int n_in,
                              void* d_out, int out_size, void* d_ws, size_t ws_size,
                              hipStream_t stream) {
  const float* x      = (const float*)d_in[0];
  const float* res    = (const float*)d_in[1];
  const float* wq_h   = (const float*)d_in[2];
  const float* wkv_h  = (const float*)d_in[3];
  const float* wo_h   = (const float*)d_in[4];
  const float* wob_h  = (const float*)d_in[5];
  const float* wq_w   = (const float*)d_in[6];
  const float* wkv_w  = (const float*)d_in[7];
  const float* wo_w   = (const float*)d_in[8];
  const float* wob_w  = (const float*)d_in[9];
  const float* conv_w = (const float*)d_in[10];
  const float* gamma  = (const float*)d_in[11];
  const float* beta   = (const float*)d_in[12];

  char* ws = (char*)d_ws;
  short* wqkvT[2] = {(short*)(ws + 0), (short*)(ws + 393216)};
  short* woT[2]   = {(short*)(ws + 786432), (short*)(ws + 917504)};
  short* convT    = (short*)(ws + 1048576);
  short* xu       = (short*)(ws + 1245184);
  float* ytmp     = (float*)(ws + 34799616);
  float* partial  = (float*)(ws + 68354048);
  float* stats    = (float*)(ws + 68485120);
  short* accb     = (short*)d_out;             // axial sum scratch in d_out
  float* out      = (float*)d_out;

  if (ws_size < 68486144ull)
    fprintf(stderr, "kernel_launch: ws_size %zu too small\n", ws_size);

  // fused weight prep: starts 0,64,192,256,384,448,512; total 592 tiles
  WtAll P;
  P.src[0] = wq_h;  P.dst[0] = wqkvT[0];          P.K[0] = 256; P.N[0] = 256; P.tile0[0] = 0;
  P.src[1] = wkv_h; P.dst[1] = wqkvT[0] + 65536;  P.K[1] = 256; P.N[1] = 512; P.tile0[1] = 64;
  P.src[2] = wq_w;  P.dst[2] = wqkvT[1];          P.K[2] = 256; P.N[2] = 256; P.tile0[2] = 192;
  P.src[3] = wkv_w; P.dst[3] = wqkvT[1] + 65536;  P.K[3] = 256; P.N[3] = 512; P.tile0[3] = 256;
  P.src[4] = wo_h;  P.dst[4] = woT[0];            P.K[4] = 256; P.N[4] = 256; P.tile0[4] = 384;
  P.src[5] = wo_w;  P.dst[5] = woT[1];            P.K[5] = 256; P.N[5] = 256; P.tile0[5] = 448;
  P.src[6] = conv_w;P.dst[6] = convT;             P.K[6] = 640; P.N[6] = 128; P.tile0[6] = 512;
  k_wt_all<<<592, 256, 0, stream>>>(P);

  k_upsample<<<dim3(512, 4), 256, 0, stream>>>(x, xu);

  k_fused<<<512, 512, 0, stream>>>(xu, wqkvT[0], woT[0], wob_h, accb, 0);
  k_fused<<<512, 512, 0, stream>>>(xu, wqkvT[1], woT[1], wob_w, accb, 1);

  k_gemm_conv<<<dim3(1, 512), 256, 0, stream>>>(accb, xu, res, convT, ytmp);
  k_bnstats1<<<128, 256, 0, stream>>>(ytmp, partial);
  k_bnstats2<<<1, 128, 0, stream>>>(partial, stats);
  k_bnout<<<512, 256, 0, stream>>>(ytmp, stats, gamma, beta, out);
}

// Round 6
// 253.617 us; speedup vs baseline: 2.8209x; 1.0679x over previous
//
#include <hip/hip_runtime.h>
#include <hip/hip_bf16.h>
#include <cstdio>

// BlockAxialUp on MI355X, round 6: k_fused LDS-op diet.
//  - merged Q/K/V production (one Xs pass, 3 MFMA per xf read)
//  - swapped-operand V production -> packed bf16x4 V^T writes
//  - swapped-operand S (S^T layout) -> per-lane softmax (2 shuffles) and
//    packed bf16x4 P writes
// Round-5 conflicts (8.4M) came from scalar 2B V/P stores; all stores are
// now >=8B packed.
//
// ws layout (bytes):
//   0        wqkvT_h bf16 [768][256]  (rows: q 0:256, k 256:512, v 512:768)
//   393216   wqkvT_w
//   786432   woT_h  bf16 [256][256]
//   917504   woT_w
//   1048576  convT  bf16 [128][640]
//   1245184  xu     bf16 [65536][256]
//   34799616 ytmp   f32  [65536][128]
//   68354048 partial f32 [128][128][2]
//   68485120 stats  f32  [128][2]
// accb (ah+aw, bf16 [65536][256]) lives in d_out; final f32 overwrites it.

typedef short bf16x8 __attribute__((ext_vector_type(8)));
typedef short bf16x4 __attribute__((ext_vector_type(4)));
typedef float f32x4 __attribute__((ext_vector_type(4)));

#define MFMA16(a, b, c) __builtin_amdgcn_mfma_f32_16x16x32_bf16((a), (b), (c), 0, 0, 0)

__device__ __forceinline__ short f2bf(float v) {
  __hip_bfloat16 h = __float2bfloat16(v);
  union { __hip_bfloat16 h; short s; } u; u.h = h; return u.s;
}
__device__ __forceinline__ float bf2f(short s) {
  return __uint_as_float(((unsigned int)(unsigned short)s) << 16);
}
// XOR swizzle, granule = 8 shorts (16 B); flips col bits 3-5 only, so any
// 4-aligned bf16x4 / 8-aligned bf16x8 access stays contiguous.
__device__ __forceinline__ int swz(int row, int col) {
  return col ^ ((row & 7) << 3);
}

// ---------------- fused weight prep: dst[n][k] = bf16(src[k][n]) ------------
struct WtAll {
  const float* src[7];
  short* dst[7];
  int K[7], N[7], tile0[7];
};

__global__ __launch_bounds__(256) void k_wt_all(WtAll P) {
  const int bid = blockIdx.x;
  int i = 0;
#pragma unroll
  for (int j = 1; j < 7; j++) if (bid >= P.tile0[j]) i = j;
  const float* src = P.src[i];
  short* dst = P.dst[i];
  const int K = P.K[i], N = P.N[i];
  const int local = bid - P.tile0[i];
  const int ktiles = K >> 5;
  const int nt = local / ktiles, kt = local - nt * ktiles;
  const int k0 = kt * 32, n0 = nt * 32;
  __shared__ float tile[32][33];
  const int tx = threadIdx.x & 31, ty = threadIdx.x >> 5;
#pragma unroll
  for (int r = 0; r < 4; r++)
    tile[ty + r * 8][tx] = src[(size_t)(k0 + ty + r * 8) * N + n0 + tx];
  __syncthreads();
#pragma unroll
  for (int r = 0; r < 4; r++)
    dst[(size_t)(n0 + ty + r * 8) * K + k0 + tx] = f2bf(tile[tx][ty + r * 8]);
}

// ---------------- upsample 2x bilinear align_corners (conflict-free) --------
__global__ __launch_bounds__(256) void k_upsample(const float* __restrict__ x,
                                                  short* __restrict__ xu) {
  __shared__ float ldsV[64][65];
  const int bh = blockIdx.x, z = blockIdx.y;
  const int b = bh >> 7, h = bh & 127;
  const float chf = h * (63.0f / 127.0f);
  int i0 = (int)chf; if (i0 > 62) i0 = 62;
  const float wh = chf - (float)i0;
  const int t = threadIdx.x;
  const int cbase = z * 64;
  const float* xb = x + ((size_t)(b * 256 + cbase) * 64 + i0) * 64;
#pragma unroll
  for (int p = 0; p < 16; p++) {
    const int li = p * 256 + t;
    const int c = li >> 6, w = li & 63;
    const float* px = xb + (size_t)c * 4096 + w;
    const float v0 = px[0], v1 = px[64];
    ldsV[c][w] = v0 * (1.f - wh) + v1 * wh;
  }
  __syncthreads();
  const int cg = t & 7, wi = t >> 3;
  short* xout = xu + (size_t)(bh * 128) * 256 + cbase + cg * 8;
#pragma unroll
  for (int p = 0; p < 4; p++) {
    const int w = p * 32 + wi;
    const float cwf = w * (63.0f / 127.0f);
    int j0 = (int)cwf; if (j0 > 62) j0 = 62;
    const float ww = cwf - (float)j0;
    bf16x8 o;
#pragma unroll
    for (int u = 0; u < 8; u++) {
      const float v0 = ldsV[cg * 8 + u][j0], v1 = ldsV[cg * 8 + u][j0 + 1];
      o[u] = f2bf(v0 * (1.f - ww) + v1 * ww);
    }
    *(bf16x8*)(xout + (size_t)w * 256) = o;
  }
}

// ---------------- fused QKV + attention + proj, one block per sequence ------
// 512 thr = 8 waves. LDS: Xs 64K + Qb(P) 32K + Kb(O) 32K + Vtb 32K = 160 KB.
__global__ __launch_bounds__(512, 2) void k_fused(const short* __restrict__ xu,
                                                  const short* __restrict__ wqkvT,
                                                  const short* __restrict__ woT,
                                                  const float* __restrict__ wob,
                                                  short* __restrict__ accb,
                                                  int dir) {
  __shared__ __align__(16) short Xs[128][256];
  __shared__ __align__(16) short Qb[128][128];   // Q, then P
  __shared__ __align__(16) short Kb[128][128];   // K, then O
  __shared__ __align__(16) short Vtb[128][128];  // V^T

  const int s = blockIdx.x;
  const int b = s >> 7, pos = s & 127;
  const int tok0 = b * 16384 + (dir ? pos * 128 : pos);
  const int tstep = dir ? 1 : 128;
  const int tid = threadIdx.x;
  const int lane = tid & 63, wid = tid >> 6;
  const int lr = lane & 15, kb = lane >> 4;
  const int ct = wid * 16;                    // wave's chan/token tile base
  const float scale = 0.08838834764831845f;  // 128^-0.5

  // ---- stage Xs: 32 lanes cover one 512 B token row ----
#pragma unroll
  for (int p = 0; p < 8; p++) {
    const int u = p * 512 + tid;
    const int row = u >> 5, ck = (u & 31) * 8;
    bf16x8 v = *(const bf16x8*)(xu + (size_t)(tok0 + row * tstep) * 256 + ck);
    *(bf16x8*)&Xs[row][swz(row, ck)] = v;
  }

  f32x4 accp[2][8];
#pragma unroll
  for (int i = 0; i < 2; i++)
#pragma unroll
    for (int j = 0; j < 8; j++) accp[i][j] = (f32x4){0.f, 0.f, 0.f, 0.f};

  for (int h = 0; h < 2; h++) {
    // weight fragments for this head (L1/L2-hot, identical across blocks)
    const short* wqb = wqkvT + (size_t)(h * 128 + ct + lr) * 256 + kb * 8;
    const short* wkb = wqkvT + (size_t)(256 + h * 128 + ct + lr) * 256 + kb * 8;
    const short* wvb = wqkvT + (size_t)(512 + h * 128 + ct + lr) * 256 + kb * 8;
    bf16x8 wq[8], wk[8], wv[8];
#pragma unroll
    for (int ks = 0; ks < 8; ks++) {
      wq[ks] = *(const bf16x8*)(wqb + ks * 32);
      wk[ks] = *(const bf16x8*)(wkb + ks * 32);
      wv[ks] = *(const bf16x8*)(wvb + ks * 32);
    }

    __syncthreads();  // A: Xs staged (h=0) / prev head's proj reads done

    // ---- merged Q/K/V production: one pass over Xs ----
#pragma unroll
    for (int nt = 0; nt < 8; nt++) {
      const int xrow = nt * 16 + lr;
      f32x4 dq = (f32x4){0.f, 0.f, 0.f, 0.f};
      f32x4 dk = (f32x4){0.f, 0.f, 0.f, 0.f};
      f32x4 dv = (f32x4){0.f, 0.f, 0.f, 0.f};
#pragma unroll
      for (int ks = 0; ks < 8; ks++) {
        bf16x8 xf = *(const bf16x8*)&Xs[xrow][swz(xrow, kb * 8 + ks * 32)];
        dq = MFMA16(wq[ks], xf, dq);   // D[chan][token]
        dk = MFMA16(wk[ks], xf, dk);   // D[chan][token]
        dv = MFMA16(xf, wv[ks], dv);   // swapped: D[token][chan]
      }
      // Q,K: lane holds chans ct+kb*4..+3 for token nt*16+lr -> packed
      const int trow = nt * 16 + lr, cc = ct + kb * 4;
      bf16x4 pq = {f2bf(dq[0]), f2bf(dq[1]), f2bf(dq[2]), f2bf(dq[3])};
      bf16x4 pk = {f2bf(dk[0]), f2bf(dk[1]), f2bf(dk[2]), f2bf(dk[3])};
      *(bf16x4*)&Qb[trow][swz(trow, cc)] = pq;
      *(bf16x4*)&Kb[trow][swz(trow, cc)] = pk;
      // V^T: lane holds tokens nt*16+kb*4..+3 for chan ct+lr -> packed
      const int vrow = ct + lr;
      bf16x4 pv = {f2bf(dv[0]), f2bf(dv[1]), f2bf(dv[2]), f2bf(dv[3])};
      *(bf16x4*)&Vtb[vrow][swz(vrow, nt * 16 + kb * 4)] = pv;
    }

    __syncthreads();  // B: Q/K/Vt visible to all waves

    // ---- S^T = K Q^T : lane owns q-token ct+lr, k = nj*16 + kb*4 + r ----
    f32x4 s8[8];
#pragma unroll
    for (int i = 0; i < 8; i++) s8[i] = (f32x4){0.f, 0.f, 0.f, 0.f};
    const int qrow = ct + lr;
#pragma unroll
    for (int ks = 0; ks < 4; ks++) {
      bf16x8 aq = *(const bf16x8*)&Qb[qrow][swz(qrow, kb * 8 + ks * 32)];
#pragma unroll
      for (int nj = 0; nj < 8; nj++) {
        const int krow = nj * 16 + lr;
        bf16x8 bk = *(const bf16x8*)&Kb[krow][swz(krow, kb * 8 + ks * 32)];
        s8[nj] = MFMA16(bk, aq, s8[nj]);   // D[k-token][q-token]
      }
    }
    // ---- softmax for q = ct+lr: 32 in-lane values + lanes kb (xor 16,32) ----
    {
      float m = s8[0][0];
#pragma unroll
      for (int nj = 0; nj < 8; nj++)
#pragma unroll
        for (int r = 0; r < 4; r++) m = fmaxf(m, s8[nj][r]);
      m = fmaxf(m, __shfl_xor(m, 16));
      m = fmaxf(m, __shfl_xor(m, 32));
      float sum = 0.f;
#pragma unroll
      for (int nj = 0; nj < 8; nj++)
#pragma unroll
        for (int r = 0; r < 4; r++) {
          s8[nj][r] = __expf((s8[nj][r] - m) * scale);
          sum += s8[nj][r];
        }
      sum += __shfl_xor(sum, 16);
      sum += __shfl_xor(sum, 32);
      const float inv = 1.f / sum;
      // P[q][k] packed: row q = ct+lr, cols nj*16 + kb*4 .. +3
#pragma unroll
      for (int nj = 0; nj < 8; nj++) {
        bf16x4 pp = {f2bf(s8[nj][0] * inv), f2bf(s8[nj][1] * inv),
                     f2bf(s8[nj][2] * inv), f2bf(s8[nj][3] * inv)};
        *(bf16x4*)&Qb[qrow][swz(qrow, nj * 16 + kb * 4)] = pp;
      }
    }

    // ---- O = P V : lane reads own P row (in-wave dep), all Vtb rows ----
    f32x4 o8[8];
#pragma unroll
    for (int i = 0; i < 8; i++) o8[i] = (f32x4){0.f, 0.f, 0.f, 0.f};
#pragma unroll
    for (int ks = 0; ks < 4; ks++) {
      bf16x8 bp = *(const bf16x8*)&Qb[qrow][swz(qrow, kb * 8 + ks * 32)];
#pragma unroll
      for (int mi = 0; mi < 8; mi++) {
        const int vrow = mi * 16 + lr;
        bf16x8 av = *(const bf16x8*)&Vtb[vrow][swz(vrow, kb * 8 + ks * 32)];
        o8[mi] = MFMA16(av, bp, o8[mi]);   // D[chan][q-token]
      }
    }

    __syncthreads();  // C: all waves' S reads of Kb done; O may overwrite

#pragma unroll
    for (int mi = 0; mi < 8; mi++) {
      const int cc = mi * 16 + kb * 4;
      bf16x4 po = {f2bf(o8[mi][0]), f2bf(o8[mi][1]), f2bf(o8[mi][2]), f2bf(o8[mi][3])};
      *(bf16x4*)&Kb[qrow][swz(qrow, cc)] = po;
    }

    __syncthreads();  // D: O complete for all waves

    // ---- proj: out-chans [wid*32, wid*32+32), all tokens ----
    {
      const short* w0 = woT + (size_t)(wid * 32 + lr) * 256 + h * 128 + kb * 8;
      const short* w1 = woT + (size_t)(wid * 32 + 16 + lr) * 256 + h * 128 + kb * 8;
      bf16x8 wa[4], wb2[4];
#pragma unroll
      for (int ks = 0; ks < 4; ks++) {
        wa[ks]  = *(const bf16x8*)(w0 + ks * 32);
        wb2[ks] = *(const bf16x8*)(w1 + ks * 32);
      }
#pragma unroll
      for (int nt = 0; nt < 8; nt++) {
        const int trow = nt * 16 + lr;
#pragma unroll
        for (int ks = 0; ks < 4; ks++) {
          bf16x8 bo = *(const bf16x8*)&Kb[trow][swz(trow, kb * 8 + ks * 32)];
          accp[0][nt] = MFMA16(wa[ks], bo, accp[0][nt]);
          accp[1][nt] = MFMA16(wb2[ks], bo, accp[1][nt]);
        }
      }
    }
  }

  // ---- accb write: token = nt*16+lr, outc = wid*32 + mi2*16 + kb*4 + r ----
#pragma unroll
  for (int mi2 = 0; mi2 < 2; mi2++) {
    const int outc = wid * 32 + mi2 * 16 + kb * 4;
    const float b0 = wob[outc], b1 = wob[outc + 1];
    const float b2 = wob[outc + 2], b3 = wob[outc + 3];
#pragma unroll
    for (int nt = 0; nt < 8; nt++) {
      const int token = tok0 + (nt * 16 + lr) * tstep;
      short* op = accb + (size_t)token * 256 + outc;
      float v0 = accp[mi2][nt][0] + b0, v1 = accp[mi2][nt][1] + b1;
      float v2 = accp[mi2][nt][2] + b2, v3 = accp[mi2][nt][3] + b3;
      if (dir) {
        bf16x4 old = *(const bf16x4*)op;
        v0 += bf2f(old[0]); v1 += bf2f(old[1]);
        v2 += bf2f(old[2]); v3 += bf2f(old[3]);
      }
      bf16x4 pv = {f2bf(v0), f2bf(v1), f2bf(v2), f2bf(v3)};
      *(bf16x4*)op = pv;
    }
  }
}

// ---------------- conv1x1: [relu(accb)|xu|res] @ convT^T -> relu -> ytmp ----
__global__ __launch_bounds__(256) void k_gemm_conv(const short* __restrict__ accb,
                                                   const short* __restrict__ xu,
                                                   const float* __restrict__ res,
                                                   const short* __restrict__ Bt,
                                                   float* __restrict__ ytmp) {
  const int tid = threadIdx.x;
  const int lane = tid & 63, wid = tid >> 6;
  const int lr = lane & 15, kb = lane >> 4;
  const int wr = wid >> 1, wc = wid & 1;
  const int m0 = blockIdx.y * 128;
  f32x4 acc[4][4];
#pragma unroll
  for (int i = 0; i < 4; i++)
#pragma unroll
    for (int j = 0; j < 4; j++) acc[i][j] = (f32x4){0.f, 0.f, 0.f, 0.f};
  const short* arow1 = accb + (size_t)(m0 + wr * 64 + lr) * 256 + kb * 8;
  const short* arow2 = xu + (size_t)(m0 + wr * 64 + lr) * 256 + kb * 8;
  const short* brow = Bt + (size_t)(wc * 64 + lr) * 640 + kb * 8;
#pragma unroll
  for (int ks = 0; ks < 8; ks++) {
    bf16x8 a[4], b[4];
#pragma unroll
    for (int mi = 0; mi < 4; mi++) {
      bf16x8 tv = *(const bf16x8*)(arow1 + (size_t)mi * 16 * 256 + ks * 32);
#pragma unroll
      for (int u = 0; u < 8; u++)
        tv[u] = ((unsigned short)tv[u] & 0x8000u) ? (short)0 : tv[u];
      a[mi] = tv;
    }
#pragma unroll
    for (int nj = 0; nj < 4; nj++)
      b[nj] = *(const bf16x8*)(brow + (size_t)nj * 16 * 640 + ks * 32);
#pragma unroll
    for (int mi = 0; mi < 4; mi++)
#pragma unroll
      for (int nj = 0; nj < 4; nj++)
        acc[mi][nj] = MFMA16(a[mi], b[nj], acc[mi][nj]);
  }
#pragma unroll
  for (int ks = 8; ks < 16; ks++) {
    bf16x8 a[4], b[4];
#pragma unroll
    for (int mi = 0; mi < 4; mi++)
      a[mi] = *(const bf16x8*)(arow2 + (size_t)mi * 16 * 256 + (ks - 8) * 32);
#pragma unroll
    for (int nj = 0; nj < 4; nj++)
      b[nj] = *(const bf16x8*)(brow + (size_t)nj * 16 * 640 + ks * 32);
#pragma unroll
    for (int mi = 0; mi < 4; mi++)
#pragma unroll
      for (int nj = 0; nj < 4; nj++)
        acc[mi][nj] = MFMA16(a[mi], b[nj], acc[mi][nj]);
  }
  const int bC = (m0 >> 14) * 128;
  const int hh = (m0 >> 7) & 127;
#pragma unroll
  for (int ks = 16; ks < 20; ks++) {
    const int e0 = (ks - 16) * 32 + kb * 8;
    bf16x8 a[4], b[4];
#pragma unroll
    for (int mi = 0; mi < 4; mi++) {
      const int wl = wr * 64 + mi * 16 + lr;
      const float* rp = res + ((size_t)(bC + e0) * 128 + hh) * 128 + wl;
      bf16x8 tv;
#pragma unroll
      for (int u = 0; u < 8; u++) tv[u] = f2bf(rp[(size_t)u * 16384]);
      a[mi] = tv;
    }
#pragma unroll
    for (int nj = 0; nj < 4; nj++)
      b[nj] = *(const bf16x8*)(brow + (size_t)nj * 16 * 640 + ks * 32);
#pragma unroll
    for (int mi = 0; mi < 4; mi++)
#pragma unroll
      for (int nj = 0; nj < 4; nj++)
        acc[mi][nj] = MFMA16(a[mi], b[nj], acc[mi][nj]);
  }
#pragma unroll
  for (int mi = 0; mi < 4; mi++) {
    const int rbase = m0 + wr * 64 + mi * 16 + kb * 4;
#pragma unroll
    for (int nj = 0; nj < 4; nj++) {
      const int c = wc * 64 + nj * 16 + lr;
#pragma unroll
      for (int r = 0; r < 4; r++)
        ytmp[(size_t)(rbase + r) * 128 + c] = fmaxf(acc[mi][nj][r], 0.f);
    }
  }
}

// ---------------- BN stats pass 1 ----------------
__global__ __launch_bounds__(256) void k_bnstats1(const float* __restrict__ y,
                                                  float* __restrict__ partial) {
  const int blk = blockIdx.x, tid = threadIdx.x;
  const int ch = tid & 127, sub = tid >> 7;
  float s = 0.f, s2 = 0.f;
  const float* p = y + (size_t)(blk * 512 + sub) * 128 + ch;
  for (int i = 0; i < 256; i++) {
    float v = p[(size_t)i * 256];
    s += v; s2 += v * v;
  }
  __shared__ float rs[2][128], rs2[2][128];
  rs[sub][ch] = s; rs2[sub][ch] = s2;
  __syncthreads();
  if (tid < 128) {
    partial[(size_t)(blk * 128 + tid) * 2]     = rs[0][tid] + rs[1][tid];
    partial[(size_t)(blk * 128 + tid) * 2 + 1] = rs2[0][tid] + rs2[1][tid];
  }
}

// ---------------- BN stats pass 2 ----------------
__global__ __launch_bounds__(128) void k_bnstats2(const float* __restrict__ partial,
                                                  float* __restrict__ stats) {
  const int ch = threadIdx.x;
  float s = 0.f, s2 = 0.f;
  for (int i = 0; i < 128; i++) {
    s  += partial[(size_t)(i * 128 + ch) * 2];
    s2 += partial[(size_t)(i * 128 + ch) * 2 + 1];
  }
  const float mu = s * (1.f / 65536.f);
  const float var = s2 * (1.f / 65536.f) - mu * mu;
  stats[ch * 2] = mu;
  stats[ch * 2 + 1] = rsqrtf(var + 1e-5f);
}

// ---------------- BN apply + transpose to (B,E,H,W) ----------------
__global__ __launch_bounds__(256) void k_bnout(const float* __restrict__ y,
                                               const float* __restrict__ stats,
                                               const float* __restrict__ gamma,
                                               const float* __restrict__ beta,
                                               float* __restrict__ out) {
  const int bh = blockIdx.x;
  const int b = bh >> 7, h = bh & 127;
  const int w = threadIdx.x & 127, eh = threadIdx.x >> 7;
  const float* yp = y + (size_t)(bh * 128 + w) * 128;
  for (int e2 = 0; e2 < 64; e2++) {
    const int e = e2 * 2 + eh;
    const float mu = stats[e * 2], rstd = stats[e * 2 + 1];
    const float v = yp[e];
    out[((size_t)(b * 128 + e) << 14) + h * 128 + w] =
        (v - mu) * rstd * gamma[e] + beta[e];
  }
}

// ---------------- launcher ----------------
extern "C" void kernel_launch(void* const* d_in, const int* in_sizes, int n_in,
                              void* d_out, int out_size, void* d_ws, size_t ws_size,
                              hipStream_t stream) {
  const float* x      = (const float*)d_in[0];
  const float* res    = (const float*)d_in[1];
  const float* wq_h   = (const float*)d_in[2];
  const float* wkv_h  = (const float*)d_in[3];
  const float* wo_h   = (const float*)d_in[4];
  const float* wob_h  = (const float*)d_in[5];
  const float* wq_w   = (const float*)d_in[6];
  const float* wkv_w  = (const float*)d_in[7];
  const float* wo_w   = (const float*)d_in[8];
  const float* wob_w  = (const float*)d_in[9];
  const float* conv_w = (const float*)d_in[10];
  const float* gamma  = (const float*)d_in[11];
  const float* beta   = (const float*)d_in[12];

  char* ws = (char*)d_ws;
  short* wqkvT[2] = {(short*)(ws + 0), (short*)(ws + 393216)};
  short* woT[2]   = {(short*)(ws + 786432), (short*)(ws + 917504)};
  short* convT    = (short*)(ws + 1048576);
  short* xu       = (short*)(ws + 1245184);
  float* ytmp     = (float*)(ws + 34799616);
  float* partial  = (float*)(ws + 68354048);
  float* stats    = (float*)(ws + 68485120);
  short* accb     = (short*)d_out;             // axial sum scratch in d_out
  float* out      = (float*)d_out;

  if (ws_size < 68486144ull)
    fprintf(stderr, "kernel_launch: ws_size %zu too small\n", ws_size);

  // fused weight prep: starts 0,64,192,256,384,448,512; total 592 tiles
  WtAll P;
  P.src[0] = wq_h;  P.dst[0] = wqkvT[0];          P.K[0] = 256; P.N[0] = 256; P.tile0[0] = 0;
  P.src[1] = wkv_h; P.dst[1] = wqkvT[0] + 65536;  P.K[1] = 256; P.N[1] = 512; P.tile0[1] = 64;
  P.src[2] = wq_w;  P.dst[2] = wqkvT[1];          P.K[2] = 256; P.N[2] = 256; P.tile0[2] = 192;
  P.src[3] = wkv_w; P.dst[3] = wqkvT[1] + 65536;  P.K[3] = 256; P.N[3] = 512; P.tile0[3] = 256;
  P.src[4] = wo_h;  P.dst[4] = woT[0];            P.K[4] = 256; P.N[4] = 256; P.tile0[4] = 384;
  P.src[5] = wo_w;  P.dst[5] = woT[1];            P.K[5] = 256; P.N[5] = 256; P.tile0[5] = 448;
  P.src[6] = conv_w;P.dst[6] = convT;             P.K[6] = 640; P.N[6] = 128; P.tile0[6] = 512;
  k_wt_all<<<592, 256, 0, stream>>>(P);

  k_upsample<<<dim3(512, 4), 256, 0, stream>>>(x, xu);

  k_fused<<<512, 512, 0, stream>>>(xu, wqkvT[0], woT[0], wob_h, accb, 0);
  k_fused<<<512, 512, 0, stream>>>(xu, wqkvT[1], woT[1], wob_w, accb, 1);

  k_gemm_conv<<<dim3(1, 512), 256, 0, stream>>>(accb, xu, res, convT, ytmp);
  k_bnstats1<<<128, 256, 0, stream>>>(ytmp, partial);
  k_bnstats2<<<1, 128, 0, stream>>>(partial, stats);
  k_bnout<<<512, 256, 0, stream>>>(ytmp, stats, gamma, beta, out);
}